// Round 10
// baseline (283.564 us; speedup 1.0000x reference)
//
#include <hip/hip_runtime.h>

// DB4 analysis low-pass h; high-pass g[n] = (-1)^n h[7-n]
#define H0 0.2303778133088964f
#define H1 0.7148465705529155f
#define H2 0.6308807679298587f
#define H3 (-0.027983769416859854f)
#define H4 (-0.18703481171888114f)
#define H5 0.030841381835986965f
#define H6 0.032883011666982945f
#define H7 (-0.010597401785069032f)

// Fused column filter: sP[m][c] = sum_j CP[m&1][j] * uH[m+(m&1)+j][c]
//                      sQ[m][c] = sum_j CQ[m&1][j] * uL[m+(m&1)+j][c]
// derived from col-analysis (8 taps) composed with col-synthesis (4 taps/parity).
struct Taps { float cp[2][14]; float cq[2][14]; };
constexpr Taps mk_taps() {
    Taps t{};
    const float h[8] = {H0, H1, H2, H3, H4, H5, H6, H7};
    const float g[8] = {H7, -H6, H5, -H4, H3, -H2, H1, -H0};
    for (int par = 0; par < 2; ++par)
        for (int j = 0; j < 14; ++j) {
            float cp = 0.f, cq = 0.f;
            for (int k = 0; k < 4; ++k) {
                int i = j - 2 * k;
                if (i >= 0 && i < 8) {
                    cp += h[2 * k + par] * h[i] + g[2 * k + par] * g[i];
                    cq += g[2 * k + par] * g[i];
                }
            }
            t.cp[par][j] = cp;
            t.cq[par][j] = cq;
        }
    return t;
}
constexpr Taps TAPS = mk_taps();

// u-array addressing: stride 32 floats/row, float4-group XOR-swizzled by (row>>1)&7
// -> column walks at even-row stride hit period-8 bank pattern (~2-way, free).
__device__ __forceinline__ int uoff(int r, int c4) {
    return r * 32 + 4 * (c4 ^ ((r >> 1) & 7));
}

// LDS layout (bytes), lifetime-overlapped:
//  A @0     : sx[46][52] (9568)                       stages 1-2
//             interior: sP@0 [32][20](2560) sQ@2560, red@5120(32)
//             boundary: y1@0 y2@1600 y3@3200 ([20][20] ea), red@5120
//  B @9568  : uL[46][32] swz (5888), uH@15456 (5888)  stage 2->3
//             boundary: sP@9568 [32][20], sQ@12128 (over dead uL)
//  total 21344 B -> 7 blocks/CU, 28 waves/CU.
__global__ __launch_bounds__(256, 7) void dwt_fused_k(const float* __restrict__ x,
                                                      float* __restrict__ out,
                                                      float* __restrict__ pmn,
                                                      float* __restrict__ pmx) {
    constexpr float h[8] = {H0, H1, H2, H3, H4, H5, H6, H7};
    constexpr float g[8] = {H7, -H6, H5, -H4, H3, -H2, H1, -H0};

    const int tileX = blockIdx.x;
    const int tileY = blockIdx.y;
    const int img = blockIdx.z;          // b*3 + c
    const int N0 = tileX * 32;
    const int M0 = tileY * 32;
    const int tid = threadIdx.x;

    __shared__ __align__(16) unsigned char smem[21344];
    float* sx = (float*)smem;                    // [46][52]
    float* y1 = (float*)smem;                    // [20][20] (boundary)
    float* y2 = (float*)(smem + 1600);
    float* y3 = (float*)(smem + 3200);
    float* red = (float*)(smem + 5120);          // [8]
    float* uL = (float*)(smem + 9568);           // [46][32] swizzled
    float* uH = (float*)(smem + 15456);          // [46][32] swizzled
    float* sPi = (float*)smem;                   // interior sP [32][20]
    float* sQi = (float*)(smem + 2560);
    float* sPb = (float*)(smem + 9568);          // boundary sP [32][20]
    float* sQb = (float*)(smem + 12128);

    const bool boundary = (tileY == 0) | (tileY == 15);
    float* sP = boundary ? sPb : sPi;
    float* sQ = boundary ? sQb : sQi;

    const float* xp = x + (size_t)img * (512 * 512);

    // ---- Stage 1: load 46x52 halo tile (base M0-7, N0-8), aligned float4 ----
    {
        const int gr0 = M0 - 7, gc0 = N0 - 8;
        for (int k = tid; k < 598; k += 256) {       // 46 rows x 13 float4
            int row = k / 13;
            int c4 = k - row * 13;
            int gr = gr0 + row;
            int gc = gc0 + 4 * c4;
            float4 v = make_float4(0.f, 0.f, 0.f, 0.f);
            if ((unsigned)gr < 512u && (unsigned)gc < 512u)
                v = *(const float4*)(xp + gr * 512 + gc);
            *(float4*)(sx + row * 52 + 4 * c4) = v;
        }
    }
    __syncthreads();

    // ---- Stage 2: row analysis -> uL/uH (swizzled) ----
    const int C0 = (N0 >> 1) - 2;
    if (tid < 230) {                                 // 46 rows x 5 col-groups
        int p = tid / 5;
        int q = tid - p * 5;
        const float4* wr = (const float4*)(sx + p * 52 + 8 * q);
        float4 w0 = wr[0], w1 = wr[1], w2 = wr[2], w3 = wr[3];
        float W[16] = {w0.x, w0.y, w0.z, w0.w, w1.x, w1.y, w1.z, w1.w,
                       w2.x, w2.y, w2.z, w2.w, w3.x, w3.y, w3.z, w3.w};
        float aL[4] = {0.f, 0.f, 0.f, 0.f}, aH[4] = {0.f, 0.f, 0.f, 0.f};
#pragma unroll
        for (int d = 0; d < 4; ++d) {
#pragma unroll
            for (int j = 0; j < 8; ++j) {
                float v = W[1 + 2 * d + j];
                aL[d] += h[j] * v;
                aH[d] += g[j] * v;
            }
            if ((unsigned)(C0 + 4 * q + d) >= 256u) { aL[d] = 0.f; aH[d] = 0.f; }
        }
        int o = uoff(p, q);
        *(float4*)(uL + o) = make_float4(aL[0], aL[1], aL[2], aL[3]);
        *(float4*)(uH + o) = make_float4(aH[0], aH[1], aH[2], aH[3]);
    }
    __syncthreads();

    if (boundary) {
        // ---- old guarded path: col analysis -> y, then col synthesis ----
        const int R0 = (M0 >> 1) - 2;
        if (tid < 100) {                             // 20 rows x 5 col-groups
            int lr = tid / 5;
            int q = tid - lr * 5;
            float a1[4] = {0.f, 0.f, 0.f, 0.f};
            float a2[4] = {0.f, 0.f, 0.f, 0.f};
            float a3[4] = {0.f, 0.f, 0.f, 0.f};
            if ((unsigned)(R0 + lr) < 256u) {
#pragma unroll
                for (int i = 0; i < 8; ++i) {
                    int o = uoff(2 * lr + i, q);
                    float4 vH = *(const float4*)(uH + o);
                    float4 vL = *(const float4*)(uL + o);
                    a1[0] += h[i] * vH.x; a1[1] += h[i] * vH.y; a1[2] += h[i] * vH.z; a1[3] += h[i] * vH.w;
                    a2[0] += g[i] * vL.x; a2[1] += g[i] * vL.y; a2[2] += g[i] * vL.z; a2[3] += g[i] * vL.w;
                    a3[0] += g[i] * vH.x; a3[1] += g[i] * vH.y; a3[2] += g[i] * vH.z; a3[3] += g[i] * vH.w;
                }
            }
            *(float4*)(y1 + lr * 20 + 4 * q) = make_float4(a1[0], a1[1], a1[2], a1[3]);
            *(float4*)(y2 + lr * 20 + 4 * q) = make_float4(a2[0], a2[1], a2[2], a2[3]);
            *(float4*)(y3 + lr * 20 + 4 * q) = make_float4(a3[0], a3[1], a3[2], a3[3]);
        }
        __syncthreads();
        if (tid < 160) {                             // 32 rows x 5 col-groups
            int m = tid / 5;
            int q = tid - m * 5;
            int mh = (m + (m & 1)) >> 1;
            int t0 = m & 1;
            float ch0 = t0 ? H1 : H0, ch1 = t0 ? H3 : H2, ch2 = t0 ? H5 : H4, ch3 = t0 ? H7 : H6;
            float cg0 = t0 ? -H6 : H7, cg1 = t0 ? -H4 : H5, cg2 = t0 ? -H2 : H3, cg3 = t0 ? -H0 : H1;
            float P[4] = {0.f, 0.f, 0.f, 0.f}, Q[4] = {0.f, 0.f, 0.f, 0.f};
#pragma unroll
            for (int k = 0; k < 4; ++k) {
                float chk = (k == 0) ? ch0 : (k == 1) ? ch1 : (k == 2) ? ch2 : ch3;
                float cgk = (k == 0) ? cg0 : (k == 1) ? cg1 : (k == 2) ? cg2 : cg3;
                float4 v1 = *(const float4*)(y1 + (mh + k) * 20 + 4 * q);
                float4 v3 = *(const float4*)(y3 + (mh + k) * 20 + 4 * q);
                float4 v2 = *(const float4*)(y2 + (mh + k) * 20 + 4 * q);
                P[0] += chk * v1.x + cgk * v3.x; P[1] += chk * v1.y + cgk * v3.y;
                P[2] += chk * v1.z + cgk * v3.z; P[3] += chk * v1.w + cgk * v3.w;
                Q[0] += cgk * v2.x; Q[1] += cgk * v2.y; Q[2] += cgk * v2.z; Q[3] += cgk * v2.w;
            }
            *(float4*)(sP + m * 20 + 4 * q) = make_float4(P[0], P[1], P[2], P[3]);
            *(float4*)(sQ + m * 20 + 4 * q) = make_float4(Q[0], Q[1], Q[2], Q[3]);
        }
    } else {
        // ---- fused col synthesis: 2 output rows/thread, 14-tap composite ----
        if (tid < 80) {                              // 16 row-pairs x 5 col-groups
            int t = tid / 5;
            int q = tid - t * 5;
            float P0[4] = {0.f, 0.f, 0.f, 0.f}, Q0[4] = {0.f, 0.f, 0.f, 0.f};
            float P1[4] = {0.f, 0.f, 0.f, 0.f}, Q1[4] = {0.f, 0.f, 0.f, 0.f};
            const int rbase = 2 * t;
#pragma unroll
            for (int rr = 0; rr < 16; ++rr) {
                int o = uoff(rbase + rr, q);
                float4 vH = *(const float4*)(uH + o);
                float4 vL = *(const float4*)(uL + o);
                if (rr <= 13) {
                    const float a = TAPS.cp[0][rr], b = TAPS.cq[0][rr];
                    P0[0] += a * vH.x; P0[1] += a * vH.y; P0[2] += a * vH.z; P0[3] += a * vH.w;
                    Q0[0] += b * vL.x; Q0[1] += b * vL.y; Q0[2] += b * vL.z; Q0[3] += b * vL.w;
                }
                if (rr >= 2) {
                    const float a = TAPS.cp[1][rr - 2], b = TAPS.cq[1][rr - 2];
                    P1[0] += a * vH.x; P1[1] += a * vH.y; P1[2] += a * vH.z; P1[3] += a * vH.w;
                    Q1[0] += b * vL.x; Q1[1] += b * vL.y; Q1[2] += b * vL.z; Q1[3] += b * vL.w;
                }
            }
            int m0 = 2 * t;
            *(float4*)(sP + m0 * 20 + 4 * q)       = make_float4(P0[0], P0[1], P0[2], P0[3]);
            *(float4*)(sP + (m0 + 1) * 20 + 4 * q) = make_float4(P1[0], P1[1], P1[2], P1[3]);
            *(float4*)(sQ + m0 * 20 + 4 * q)       = make_float4(Q0[0], Q0[1], Q0[2], Q0[3]);
            *(float4*)(sQ + (m0 + 1) * 20 + 4 * q) = make_float4(Q1[0], Q1[1], Q1[2], Q1[3]);
        }
    }
    __syncthreads();

    // ---- Stage 5: row synthesis, 8 outputs/thread, float4 stores + min/max ----
    float lmn = 3.4e38f, lmx = -3.4e38f;
    if (tid < 128) {                                 // 32 rows x 4 groups of 8 cols
        int m = tid >> 2;
        int qq = tid & 3;
        const float* pp = sP + m * 20 + 4 * qq;
        const float* qp = sQ + m * 20 + 4 * qq;
        float4 pa = *(const float4*)pp, pb = *(const float4*)(pp + 4);
        float4 qa = *(const float4*)qp, qb = *(const float4*)(qp + 4);
        float sp[8] = {pa.x, pa.y, pa.z, pa.w, pb.x, pb.y, pb.z, pb.w};
        float sq[8] = {qa.x, qa.y, qa.z, qa.w, qb.x, qb.y, qb.z, qb.w};
        float val[8];
#pragma unroll
        for (int e = 0; e < 8; ++e) {
            const int t0 = e & 1;
            const int r0 = (e + (e & 1)) >> 1;
            float r = g[t0] * sp[r0] + g[t0 + 2] * sp[r0 + 1] + g[t0 + 4] * sp[r0 + 2] + g[t0 + 6] * sp[r0 + 3]
                    + h[t0] * sq[r0] + h[t0 + 2] * sq[r0 + 1] + h[t0 + 4] * sq[r0 + 2] + h[t0 + 6] * sq[r0 + 3];
            val[e] = r;
            lmn = fminf(lmn, r);
            lmx = fmaxf(lmx, r);
        }
        float* op = out + ((size_t)img * 512 + (M0 + m)) * 512 + (N0 + 8 * qq);
        *(float4*)op = make_float4(val[0], val[1], val[2], val[3]);
        *(float4*)(op + 4) = make_float4(val[4], val[5], val[6], val[7]);
    }

    // block reduce -> one partial pair per block (no atomics)
#pragma unroll
    for (int off = 32; off > 0; off >>= 1) {
        lmn = fminf(lmn, __shfl_down(lmn, off));
        lmx = fmaxf(lmx, __shfl_down(lmx, off));
    }
    int wv = tid >> 6;
    if ((tid & 63) == 0) { red[wv] = lmn; red[4 + wv] = lmx; }
    __syncthreads();
    if (tid == 0) {
        float mn = fminf(fminf(red[0], red[1]), fminf(red[2], red[3]));
        float mx = fmaxf(fmaxf(red[4], red[5]), fmaxf(red[6], red[7]));
        int blin = (img * 16 + tileY) * 16 + tileX;  // 0..24575
        pmn[blin] = mn;
        pmx[blin] = mx;
    }
}

// 32 blocks (one per sample): fold 768 partials -> mn[32], mx[32]
__global__ __launch_bounds__(256) void minmax_reduce_k(const float* __restrict__ pmn,
                                                       const float* __restrict__ pmx,
                                                       float* __restrict__ mnmx) {
    __shared__ float r[8];
    int s = blockIdx.x;
    int tid = threadIdx.x;
    int base = s * 768;
    float lmn = 3.4e38f, lmx = -3.4e38f;
#pragma unroll
    for (int k = 0; k < 3; ++k) {
        lmn = fminf(lmn, pmn[base + tid + 256 * k]);
        lmx = fmaxf(lmx, pmx[base + tid + 256 * k]);
    }
#pragma unroll
    for (int off = 32; off > 0; off >>= 1) {
        lmn = fminf(lmn, __shfl_down(lmn, off));
        lmx = fmaxf(lmx, __shfl_down(lmx, off));
    }
    int wv = tid >> 6;
    if ((tid & 63) == 0) { r[wv] = lmn; r[4 + wv] = lmx; }
    __syncthreads();
    if (tid == 0) {
        mnmx[s]      = fminf(fminf(r[0], r[1]), fminf(r[2], r[3]));
        mnmx[32 + s] = fmaxf(fmaxf(r[4], r[5]), fmaxf(r[6], r[7]));
    }
}

// 2048 blocks: b -> sample s = b>>6, chunk c = b&63 (3072 float4 each).
__global__ __launch_bounds__(256) void normalize_k(float* __restrict__ out,
                                                   const float* __restrict__ mnmx) {
    const int b = blockIdx.x;
    const int s = b >> 6;
    const int c = b & 63;
    const int tid = threadIdx.x;
    const float mn = mnmx[s];
    const float inv = 1.0f / (mnmx[32 + s] - mn + 1e-8f);
    float4* o4 = (float4*)out;
    const size_t base4 = (size_t)s * 196608 + (size_t)c * 3072;
#pragma unroll
    for (int it = 0; it < 12; ++it) {
        size_t i = base4 + it * 256 + tid;
        float4 v = o4[i];
        v.x = (v.x - mn) * inv;
        v.y = (v.y - mn) * inv;
        v.z = (v.z - mn) * inv;
        v.w = (v.w - mn) * inv;
        o4[i] = v;
    }
}

extern "C" void kernel_launch(void* const* d_in, const int* in_sizes, int n_in,
                              void* d_out, int out_size, void* d_ws, size_t ws_size,
                              hipStream_t stream) {
    const float* x = (const float*)d_in[0];
    float* out = (float*)d_out;
    float* wsf = (float*)d_ws;
    float* pmn = wsf;                 // 24576
    float* pmx = wsf + 24576;         // 24576
    float* mnmx = wsf + 49152;        // 64

    hipLaunchKernelGGL(dwt_fused_k, dim3(16, 16, 96), dim3(256), 0, stream, x, out, pmn, pmx);
    hipLaunchKernelGGL(minmax_reduce_k, dim3(32), dim3(256), 0, stream, pmn, pmx, mnmx);
    hipLaunchKernelGGL(normalize_k, dim3(2048), dim3(256), 0, stream, out, mnmx);
}